// Round 3
// baseline (2404.029 us; speedup 1.0000x reference)
//
#include <hip/hip_runtime.h>
#include <hip/hip_bf16.h>
#include <math.h>

// Problem dims
#define VOCAB 50001
#define EDIM 256
#define HDIM 256          // per-direction hidden
#define GDIM 1024         // 4*HDIM gates
#define KTAG 9
#define NB 64             // batch
#define NT 256            // time

// workspace layout (float offsets)
static constexpr size_t XP_OFF    = 0;                          // xproj [16384][2048]
static constexpr size_t HX_OFF    = XP_OFF + (size_t)16384*2048;// h exchange [2][256][128]
static constexpr size_t FLAGS_OFF = HX_OFF + 65536;             // 256 ints (pad 512)
static constexpr size_t BIAS_OFF  = FLAGS_OFF + 512;            // [2048]
static constexpr size_t HS_OFF    = BIAS_OFF + 2048;            // hstore [16384][512]
static constexpr size_t EM_OFF    = HS_OFF + (size_t)16384*512; // emissions [16384][9]

// readlane: h is wave-uniform -> SGPR operand for fma
#define RL(v, l) __int_as_float(__builtin_amdgcn_readlane(__float_as_int(v), (l)))

// ---------------------------------------------------------------------------
// Prep: combined bias b_ih+b_hh, zero exchange flags (each launch -> replay-safe).
__global__ __launch_bounds__(256) void k_prep(const float* __restrict__ bif,
                                              const float* __restrict__ bhf,
                                              const float* __restrict__ bib,
                                              const float* __restrict__ bhb,
                                              float* __restrict__ ws) {
    int t = blockIdx.x * 256 + threadIdx.x;   // grid 16x256 = 4096
    float* bias = ws + BIAS_OFF;
    if (t < 2048) {
        int d = t >> 10, g = t & 1023;
        bias[t] = d ? (bib[g] + bhb[g]) : (bif[g] + bhf[g]);
    }
    int* flags = (int*)(ws + FLAGS_OFF);
    if (t < 256) flags[t] = 0;
}

// ---------------------------------------------------------------------------
// xproj GEMM: M=16384 rows (r = t*64+b, A row = embed[x[b,t]]), N=2048
// (w_ih_f rows 0..1023 | w_ih_b rows 1024..2047), K=256. fp32, 64x64 tiles.
#define BKC 32
__global__ __launch_bounds__(256) void k_xproj(const int* __restrict__ x,
                                               const float* __restrict__ embed,
                                               const float* __restrict__ wih_f,
                                               const float* __restrict__ wih_b,
                                               float* __restrict__ ws) {
    float* xp = ws + XP_OFF;
    const float* bias = ws + BIAS_OFF;
    __shared__ float As[BKC][68];
    __shared__ float Bs[BKC][68];
    __shared__ int ids[64];
    const int bm = blockIdx.x;      // 0..255
    const int bn = blockIdx.y;      // 0..31
    const int tid = threadIdx.x;
    const int tx = tid & 15, ty = tid >> 4;

    if (tid < 64) {
        int r = bm * 64 + tid;
        int t = r >> 6, b = r & 63;
        ids[tid] = x[b * 256 + t];
    }
    __syncthreads();

    float acc[4][4];
#pragma unroll
    for (int i = 0; i < 4; ++i)
#pragma unroll
        for (int j = 0; j < 4; ++j) acc[i][j] = 0.f;

    const int lm = tid >> 2;
    const int lks = (tid & 3) * 8;

    for (int k0 = 0; k0 < 256; k0 += BKC) {
        {
            const float* src = embed + (size_t)ids[lm] * 256 + k0 + lks;
            float4 a0 = *reinterpret_cast<const float4*>(src);
            float4 a1 = *reinterpret_cast<const float4*>(src + 4);
            As[lks + 0][lm] = a0.x; As[lks + 1][lm] = a0.y;
            As[lks + 2][lm] = a0.z; As[lks + 3][lm] = a0.w;
            As[lks + 4][lm] = a1.x; As[lks + 5][lm] = a1.y;
            As[lks + 6][lm] = a1.z; As[lks + 7][lm] = a1.w;
        }
        {
            int gn = bn * 64 + lm;
            const float* wsrc = (gn < 1024) ? (wih_f + (size_t)gn * 256)
                                            : (wih_b + (size_t)(gn - 1024) * 256);
            const float* src = wsrc + k0 + lks;
            float4 b0 = *reinterpret_cast<const float4*>(src);
            float4 b1 = *reinterpret_cast<const float4*>(src + 4);
            Bs[lks + 0][lm] = b0.x; Bs[lks + 1][lm] = b0.y;
            Bs[lks + 2][lm] = b0.z; Bs[lks + 3][lm] = b0.w;
            Bs[lks + 4][lm] = b1.x; Bs[lks + 5][lm] = b1.y;
            Bs[lks + 6][lm] = b1.z; Bs[lks + 7][lm] = b1.w;
        }
        __syncthreads();
#pragma unroll
        for (int k = 0; k < BKC; ++k) {
            float4 a = *reinterpret_cast<const float4*>(&As[k][ty * 4]);
            float4 bq = *reinterpret_cast<const float4*>(&Bs[k][tx * 4]);
            acc[0][0] += a.x * bq.x; acc[0][1] += a.x * bq.y; acc[0][2] += a.x * bq.z; acc[0][3] += a.x * bq.w;
            acc[1][0] += a.y * bq.x; acc[1][1] += a.y * bq.y; acc[1][2] += a.y * bq.z; acc[1][3] += a.y * bq.w;
            acc[2][0] += a.z * bq.x; acc[2][1] += a.z * bq.y; acc[2][2] += a.z * bq.z; acc[2][3] += a.z * bq.w;
            acc[3][0] += a.w * bq.x; acc[3][1] += a.w * bq.y; acc[3][2] += a.w * bq.z; acc[3][3] += a.w * bq.w;
        }
        __syncthreads();
    }

    const int gm = bm * 64 + ty * 4;
    const int gn = bn * 64 + tx * 4;
#pragma unroll
    for (int i = 0; i < 4; ++i) {
        float4 o;
        o.x = acc[i][0] + bias[gn + 0];
        o.y = acc[i][1] + bias[gn + 1];
        o.z = acc[i][2] + bias[gn + 2];
        o.w = acc[i][3] + bias[gn + 3];
        *reinterpret_cast<float4*>(xp + (size_t)(gm + i) * 2048 + gn) = o;
    }
}

// ---------------------------------------------------------------------------
// Recurrence v2: weights fully CU-resident.
// 256 blocks = (half, dir, batch); 512 threads = gate-rows (gt*128+jj) of the
// block's j-half. w row: k[0,192) in VGPRs (48 float4), k[192,256) in LDS.
// h (256 f) wave-uniform via ds_read_b128 + v_readlane -> SGPR fma operand.
// Pairwise h-half exchange with partner block (blk^128) via agent-scope
// atomics; per-step monotone flags (prep-zeroed), double-buffered data.
#define WREGS 48
#define WLDSC 16
#define REC_LDS_FLOATS (WLDSC * 512 * 4 + 256 + 512)

__global__ __launch_bounds__(512, 2) void k_rec2(const float* __restrict__ whh_f,
                                                 const float* __restrict__ whh_b,
                                                 float* __restrict__ ws) {
    extern __shared__ float sm[];
    float* wlds = sm;                       // [WLDSC][512][4]
    float* hbuf = sm + WLDSC * 512 * 4;     // [256]
    float* gact = hbuf + 256;               // [512]

    const float* xp = ws + XP_OFF;
    float* hx = ws + HX_OFF;
    int* flags = (int*)(ws + FLAGS_OFF);
    float* hs = ws + HS_OFF;

    const int blk = blockIdx.x;
    const int jhalf = blk >> 7;             // which h-half this block owns
    const int dir = (blk >> 6) & 1;
    const int batch = blk & 63;
    const int partner = blk ^ 128;          // same dir,batch, other half (same XCD slot mod 8)
    const int t = threadIdx.x;
    const int gt = t >> 7;                  // 0:i 1:f 2:g 3:o (wave-uniform)
    const int jj = t & 127;
    const int row_global = gt * 256 + jhalf * 128 + jj;
    const int col = dir * 1024 + row_global;
    const float* wrow = (dir ? whh_b : whh_f) + (size_t)row_global * 256;

    // ---- preload weights: 192 floats -> VGPR, 64 floats -> LDS
    float4 w4[WREGS];
#pragma unroll
    for (int i = 0; i < WREGS; ++i) w4[i] = *reinterpret_cast<const float4*>(wrow + i * 4);
#pragma unroll
    for (int c = 0; c < WLDSC; ++c)
        *reinterpret_cast<float4*>(&wlds[((size_t)c * 512 + t) * 4]) =
            *reinterpret_cast<const float4*>(wrow + 192 + c * 4);

    if (t < 256) hbuf[t] = 0.f;
    float creg = 0.f;
    __syncthreads();

    const int lane = t & 63;
    float xpv_next = xp[((size_t)((dir ? 255 : 0) * 64 + batch)) * 2048 + col];

    for (int s = 0; s < 256; ++s) {
        const int tt = dir ? (255 - s) : s;
        const float xpv = xpv_next;

        // h (wave-uniform): every wave reads the full 256-float hbuf
        float4 vh = *reinterpret_cast<const float4*>(&hbuf[lane * 4]);

        float a0 = 0.f, a1 = 0.f, a2 = 0.f, a3 = 0.f;
#pragma unroll
        for (int i = 0; i < WREGS; ++i) {
            a0 += w4[i].x * RL(vh.x, i);   // h[4i+0]
            a1 += w4[i].y * RL(vh.y, i);   // h[4i+1]
            a2 += w4[i].z * RL(vh.z, i);   // h[4i+2]
            a3 += w4[i].w * RL(vh.w, i);   // h[4i+3]
        }
#pragma unroll
        for (int c = 0; c < WLDSC; ++c) {
            float4 wl = *reinterpret_cast<const float4*>(&wlds[((size_t)c * 512 + t) * 4]);
            const int l = WREGS + c;
            a0 += wl.x * RL(vh.x, l);
            a1 += wl.y * RL(vh.y, l);
            a2 += wl.z * RL(vh.z, l);
            a3 += wl.w * RL(vh.w, l);
        }
        const float acc = xpv + ((a0 + a1) + (a2 + a3));

        const float act = (gt == 2) ? tanhf(acc) : 1.f / (1.f + expf(-acc));
        gact[t] = act;
        __syncthreads();

        float hval = 0.f;
        if (t < 128) {   // waves 0,1 exactly -> uniform branch
            const float si = gact[t], sf = gact[128 + t], tg = gact[256 + t], so = gact[384 + t];
            creg = sf * creg + si * tg;
            hval = so * tanhf(creg);
            __hip_atomic_store(&hx[((size_t)(s & 1) * 256 + blk) * 128 + t], hval,
                               __ATOMIC_RELAXED, __HIP_MEMORY_SCOPE_AGENT);
            asm volatile("s_waitcnt vmcnt(0)" ::: "memory");  // own store globally visible
        }
        __syncthreads();

        if (t == 0)
            __hip_atomic_store(&flags[blk], s + 1, __ATOMIC_RELEASE, __HIP_MEMORY_SCOPE_AGENT);

        // issue next-step xp load into the exchange window
        {
            const int sn = (s < 255) ? s + 1 : 255;
            const int ttn = dir ? (255 - sn) : sn;
            xpv_next = xp[((size_t)(ttn * 64 + batch)) * 2048 + col];
        }
        if (t < 128) {
            hbuf[jhalf * 128 + t] = hval;
            hs[((size_t)(tt * 64 + batch)) * 512 + dir * 256 + jhalf * 128 + t] = hval;
        }

        if (t == 0) {
            while (__hip_atomic_load(&flags[partner], __ATOMIC_ACQUIRE,
                                     __HIP_MEMORY_SCOPE_AGENT) < s + 1) {
                __builtin_amdgcn_s_sleep(2);
            }
        }
        __syncthreads();
        if (t < 128) {
            float hp = __hip_atomic_load(&hx[((size_t)(s & 1) * 256 + partner) * 128 + t],
                                         __ATOMIC_RELAXED, __HIP_MEMORY_SCOPE_AGENT);
            hbuf[(1 - jhalf) * 128 + t] = hp;
        }
        __syncthreads();
    }
}

// ---------------------------------------------------------------------------
// Emissions: em[r][j] = dot(hstore[r][0:512], w_out[j]) + b_out[j]
__global__ __launch_bounds__(256) void k_emis(const float* __restrict__ wout,
                                              const float* __restrict__ bout,
                                              float* __restrict__ ws) {
    const float* hs = ws + HS_OFF;
    float* em = ws + EM_OFF;
    __shared__ float wl[9][512];
    __shared__ float bl[9];
    const int tid = threadIdx.x;
    for (int i = tid; i < 9 * 512; i += 256) wl[i / 512][i % 512] = wout[i];
    if (tid < 9) bl[tid] = bout[tid];
    __syncthreads();

    const int r = blockIdx.x * 256 + tid;
    const float4* hrow = reinterpret_cast<const float4*>(hs + (size_t)r * 512);
    float acc[9];
#pragma unroll
    for (int j = 0; j < 9; ++j) acc[j] = bl[j];
    for (int k4 = 0; k4 < 128; ++k4) {
        float4 h = hrow[k4];
#pragma unroll
        for (int j = 0; j < 9; ++j) {
            float4 w = *reinterpret_cast<const float4*>(&wl[j][k4 * 4]);
            acc[j] += h.x * w.x + h.y * w.y + h.z * w.z + h.w * w.w;
        }
    }
#pragma unroll
    for (int j = 0; j < 9; ++j) em[(size_t)r * 9 + j] = acc[j];
}

// ---------------------------------------------------------------------------
// Viterbi: one block per batch; strict-> first-index argmax matches jnp.
__global__ __launch_bounds__(64) void k_vit(const float* __restrict__ start,
                                            const float* __restrict__ endv,
                                            const float* __restrict__ trans,
                                            const float* __restrict__ ws_c,
                                            float* __restrict__ out) {
    const float* em = ws_c + EM_OFF;
    const int b = blockIdx.x;
    const int lane = threadIdx.x;
    __shared__ float tr[81];
    __shared__ float sc[9];
    __shared__ float ns[9];
    __shared__ int hist[256][9];

    for (int i = lane; i < 81; i += 64) tr[i] = trans[i];
    if (lane < 9) sc[lane] = start[lane] + em[(size_t)b * 9 + lane];
    __syncthreads();

    for (int t = 1; t < 256; ++t) {
        if (lane < 9) {
            float e = em[((size_t)t * 64 + b) * 9 + lane];
            float best = -1e30f; int bi = 0;
#pragma unroll
            for (int i = 0; i < 9; ++i) {
                float v = sc[i] + tr[i * 9 + lane];
                if (v > best) { best = v; bi = i; }
            }
            ns[lane] = best + e;
            hist[t][lane] = bi;
        }
        __syncthreads();
        if (lane < 9) sc[lane] = ns[lane];
        __syncthreads();
    }

    if (lane == 0) {
        float best = -1e30f; int bi = 0;
        for (int j = 0; j < 9; ++j) {
            float v = sc[j] + endv[j];
            if (v > best) { best = v; bi = j; }
        }
        out[16384 + b] = best;
        int cur = bi;
        out[(size_t)b * 256 + 255] = (float)cur;
        for (int t = 255; t >= 1; --t) {
            cur = hist[t][cur];
            out[(size_t)b * 256 + t - 1] = (float)cur;
        }
    }
}

// ---------------------------------------------------------------------------
extern "C" void kernel_launch(void* const* d_in, const int* in_sizes, int n_in,
                              void* d_out, int out_size, void* d_ws, size_t ws_size,
                              hipStream_t stream) {
    (void)in_sizes; (void)n_in; (void)out_size; (void)ws_size;
    const int*   x       = (const int*)d_in[0];
    const float* embed   = (const float*)d_in[1];
    const float* w_ih_f  = (const float*)d_in[2];
    const float* w_hh_f  = (const float*)d_in[3];
    const float* b_ih_f  = (const float*)d_in[4];
    const float* b_hh_f  = (const float*)d_in[5];
    const float* w_ih_b  = (const float*)d_in[6];
    const float* w_hh_b  = (const float*)d_in[7];
    const float* b_ih_b  = (const float*)d_in[8];
    const float* b_hh_b  = (const float*)d_in[9];
    const float* w_out   = (const float*)d_in[10];
    const float* b_out   = (const float*)d_in[11];
    const float* crf_start = (const float*)d_in[12];
    const float* crf_end   = (const float*)d_in[13];
    const float* crf_trans = (const float*)d_in[14];
    float* ws  = (float*)d_ws;
    float* out = (float*)d_out;

    const size_t rec_lds_bytes = (size_t)REC_LDS_FLOATS * 4;   // 134,144 B
    hipFuncSetAttribute(reinterpret_cast<const void*>(k_rec2),
                        hipFuncAttributeMaxDynamicSharedMemorySize,
                        (int)rec_lds_bytes);

    hipLaunchKernelGGL(k_prep, dim3(16), dim3(256), 0, stream,
                       b_ih_f, b_hh_f, b_ih_b, b_hh_b, ws);
    hipLaunchKernelGGL(k_xproj, dim3(256, 32), dim3(256), 0, stream,
                       x, embed, w_ih_f, w_ih_b, ws);
    hipLaunchKernelGGL(k_rec2, dim3(256), dim3(512), rec_lds_bytes, stream,
                       w_hh_f, w_hh_b, ws);
    hipLaunchKernelGGL(k_emis, dim3(64), dim3(256), 0, stream, w_out, b_out, ws);
    hipLaunchKernelGGL(k_vit, dim3(64), dim3(64), 0, stream,
                       crf_start, crf_end, crf_trans, ws, out);
}